// Round 3
// baseline (5773.545 us; speedup 1.0000x reference)
//
#include <hip/hip_runtime.h>
#include <hip/hip_fp16.h>

#define NB 128
#define TT 256
#define MM 256
#define PP 256

typedef unsigned int uint;
typedef _Float16 hf2 __attribute__((ext_vector_type(2)));

__device__ __forceinline__ float dot2f(uint a, uint b, float c){
#if defined(__AMDGCN__) && __has_builtin(__builtin_amdgcn_fdot2)
    return __builtin_amdgcn_fdot2(__builtin_bit_cast(hf2, a), __builtin_bit_cast(hf2, b), c, false);
#else
    float2 fa = __half22float2(__builtin_bit_cast(__half2, a));
    float2 fb = __half22float2(__builtin_bit_cast(__half2, b));
    return fmaf(fa.x, fb.x, fmaf(fa.y, fb.y, c));
#endif
}

__device__ __forceinline__ float frcp(float x){ return __builtin_amdgcn_rcpf(x); }
__device__ __forceinline__ float fsig(float x){ return frcp(1.f + __expf(-x)); }
__device__ __forceinline__ float ftanh(float x){ return fmaf(-2.f, frcp(1.f + __expf(2.f*x)), 1.f); }

__device__ __forceinline__ float wsum(float v){
    #pragma unroll
    for(int o=32;o;o>>=1) v += __shfl_xor(v,o);
    return v;
}
__device__ __forceinline__ float wmax(float v){
    #pragma unroll
    for(int o=32;o;o>>=1) v = fmaxf(v,__shfl_xor(v,o));
    return v;
}

// pre[row, m] = sum_k enc[row, k] * W1[k, m] + b1[m] -> fp16
__global__ __launch_bounds__(256) void prep_pre(
    const float* __restrict__ enc, const float* __restrict__ W1,
    const float* __restrict__ b1, __half* __restrict__ pre)
{
    const int row0 = blockIdx.x * 32;
    const int col  = threadIdx.x;
    float acc[32];
    const float bias = b1[col];
    #pragma unroll
    for (int r=0;r<32;++r) acc[r]=bias;
    for (int k=0;k<256;k+=4){
        const float w0 = W1[(size_t)(k+0)*256+col];
        const float w1 = W1[(size_t)(k+1)*256+col];
        const float w2 = W1[(size_t)(k+2)*256+col];
        const float w3 = W1[(size_t)(k+3)*256+col];
        #pragma unroll
        for (int r=0;r<32;++r){
            const float4 e = *(const float4*)(enc + (size_t)(row0+r)*256 + k);
            acc[r] = fmaf(e.x,w0, fmaf(e.y,w1, fmaf(e.z,w2, fmaf(e.w,w3, acc[r]))));
        }
    }
    #pragma unroll
    for (int r=0;r<32;++r) pre[(size_t)(row0+r)*256+col] = __float2half(acc[r]);
}

// Wr (256,1024) f32 -> k-pair-interleaved half2: Wp[k2*1024 + j] = (Wr[2k2][j], Wr[2k2+1][j])
__global__ __launch_bounds__(256) void pack_wr(const float* __restrict__ Wr, __half2* __restrict__ Wp){
    const int idx = blockIdx.x*256 + threadIdx.x;   // 131072
    const int k2 = idx >> 10, j = idx & 1023;
    Wp[idx] = __floats2half2_rn(Wr[(size_t)(2*k2)*1024 + j], Wr[(size_t)(2*k2+1)*1024 + j]);
}
// W2 (512,256) f32 -> Wp[k2*256 + m]
__global__ __launch_bounds__(256) void pack_w2(const float* __restrict__ W2, __half2* __restrict__ Wp){
    const int idx = blockIdx.x*256 + threadIdx.x;   // 65536
    const int k2 = idx >> 8, m = idx & 255;
    Wp[idx] = __floats2half2_rn(W2[(size_t)(2*k2)*256 + m], W2[(size_t)(2*k2+1)*256 + m]);
}
// edot[row] = enc[row,:] . Wd[1:257]   (one 64-lane wave per row)
__global__ __launch_bounds__(256) void prep_edot(
    const float* __restrict__ enc, const float* __restrict__ Wd, float* __restrict__ edot)
{
    const int row  = blockIdx.x*4 + (threadIdx.x>>6);
    const int lane = threadIdx.x & 63;
    const float4 e = *(const float4*)(enc + (size_t)row*256 + lane*4);
    float s = e.x*Wd[1+lane*4] + e.y*Wd[2+lane*4] + e.z*Wd[3+lane*4] + e.w*Wd[4+lane*4];
    s = wsum(s);
    if (lane==0) edot[row] = s;
}

// One block per batch element; 1024 threads; full 255-step recurrence in-kernel.
__global__ __launch_bounds__(1024) void decoder_kernel(
    const float* __restrict__ data, const float* __restrict__ enc,
    const float* __restrict__ h0, const float* __restrict__ c0,
    const float* __restrict__ Wd, const float* __restrict__ bd,
    const float* __restrict__ Wk, const float* __restrict__ bl,
    const float* __restrict__ b2, const float* __restrict__ Wv,
    const float* __restrict__ bv,
    const uint4* __restrict__ Wr_p,   // [128 k2][256 uint4]
    const uint4* __restrict__ W2_p,   // [256 k2][64 uint4]
    const __half* __restrict__ pre,   // [B*T][256]
    const float* __restrict__ edot,   // [B*T]
    float* __restrict__ out)
{
    __shared__ float s_h[PP], s_c[PP], s_q[MM], s_score[TT];
    __shared__ float s_red[4096];
    __shared__ float s_r2[32];
    __shared__ float s_Wk[1024], s_bl[1024], s_b2[MM], s_Wv[MM];
    __shared__ float s_edot[TT], s_data[TT];
    __shared__ float s_sc2[4];
    __shared__ __half s_hh[PP], s_ch[PP];

    const int b    = blockIdx.x;
    const int tid  = threadIdx.x;
    const int lane = tid & 63;
    const int wid  = tid >> 6;

    s_Wk[tid] = Wk[tid];
    s_bl[tid] = bl[tid];
    if (tid < MM){
        s_b2[tid] = b2[tid];
        s_Wv[tid] = Wv[tid];
        const float h0v = h0[(size_t)b*PP+tid];
        const float c0v = c0[(size_t)b*PP+tid];
        s_h[tid]  = h0v;  s_hh[tid] = __float2half(h0v);
        s_c[tid]  = c0v;  s_ch[tid] = __float2half(c0v);
        s_edot[tid] = edot[(size_t)b*TT + tid];
    }
    if (tid < TT-1) s_data[tid] = data[(size_t)b*(TT-1)+tid];
    if (tid < 8)  s_r2[20+tid] = (tid==0) ? 1.f : 0.f;   // den=1, num=0 -> ctx term 0
    if (tid == 0){ s_sc2[0] = bd[0]; s_sc2[1] = bv[0]; s_sc2[2] = Wd[0]; }
    __syncthreads();

    const __half* prow_b = pre + (size_t)b*TT*MM;
    const float*  erow_b = enc + (size_t)b*TT*MM;

    const int jq  = tid & 255;   // A: j-quad
    const int kc  = tid >> 8;    // A: k2-chunk 0..3 (32 k2 each)
    const int mq  = tid & 63;    // B/epilogue: m-quad
    const int kc2 = tid >> 6;    // B: k2-chunk 0..15; epilogue: t-chunk
    const int ttx = tid >> 2;    // C: t index
    const int sub = tid & 3;     // C: m sub-chunk

    // ---- prologue: z-partials for h0 ----
    {
        float4 za = make_float4(0.f,0.f,0.f,0.f);
        const uint4* wp = Wr_p + (size_t)(kc*32)*256 + jq;
        const uint*  hu = ((const uint*)s_hh) + kc*32;
        #pragma unroll 8
        for (int i=0;i<32;++i){
            const uint4 w = wp[(size_t)i*256];
            const uint hv = hu[i];
            za.x = dot2f(w.x,hv,za.x); za.y = dot2f(w.y,hv,za.y);
            za.z = dot2f(w.z,hv,za.z); za.w = dot2f(w.w,hv,za.w);
        }
        *(float4*)&s_red[kc*1024 + jq*4] = za;
    }
    __syncthreads();

    for (int t=0; t<TT-1; ++t){
        // ---- Phase 1: gates (256 threads) ----
        if (tid < PP){
            const float den = s_r2[20]+s_r2[21]+s_r2[22]+s_r2[23];
            const float num = s_r2[24]+s_r2[25]+s_r2[26]+s_r2[27];
            const float xin = num*frcp(den) + s_data[t]*s_sc2[2] + s_sc2[0];
            float z[4];
            #pragma unroll
            for (int g=0; g<4; ++g){
                const int j = tid + 256*g;
                float zz = s_red[j] + s_red[1024+j] + s_red[2048+j] + s_red[3072+j];
                z[g] = zz + xin*s_Wk[j] + s_bl[j];
            }
            const float gi = fsig(z[0]);
            const float gf = fsig(z[1]);
            const float gg = ftanh(z[2]);
            const float go = fsig(z[3]);
            const float c_new = gf*s_c[tid] + gi*gg;
            const float h_new = go*ftanh(c_new);
            s_c[tid] = c_new;
            s_h[tid] = h_new;
            s_hh[tid] = __float2half(h_new);
            s_ch[tid] = __float2half(c_new);
        }
        __syncthreads();

        // ---- Phase 2: q partials, [h;c] @ W2 via dot2 ----
        {
            float4 qa = make_float4(0.f,0.f,0.f,0.f);
            const uint4* wp = W2_p + (size_t)(kc2*16)*64 + mq;
            const uint*  hb = (kc2 < 8) ? (const uint*)s_hh : (((const uint*)s_ch) - 128);
            #pragma unroll 8
            for (int i=0;i<16;++i){
                const uint4 w = wp[(size_t)i*64];
                const uint hv = hb[kc2*16 + i];
                qa.x = dot2f(w.x,hv,qa.x); qa.y = dot2f(w.y,hv,qa.y);
                qa.z = dot2f(w.z,hv,qa.z); qa.w = dot2f(w.w,hv,qa.w);
            }
            *(float4*)&s_red[kc2*256 + mq*4] = qa;
        }
        __syncthreads();

        // ---- Phase 3: q reduce (256 threads) ----
        if (tid < MM){
            float q = s_b2[tid];
            #pragma unroll
            for (int i=0;i<16;++i) q += s_red[i*256+tid];
            s_q[tid] = q;
        }
        __syncthreads();

        // ---- Phase 4 (fused): scores (tanh) + next-step z-partials (Wr stream) ----
        {
            float4 za = make_float4(0.f,0.f,0.f,0.f);
            float sacc = 0.f;
            const uint4* wp = Wr_p + (size_t)(kc*32)*256 + jq;
            const uint*  hu = ((const uint*)s_hh) + kc*32;
            const uint4* prow = (const uint4*)(prow_b + (size_t)ttx*MM);
            #pragma unroll
            for (int cch=0; cch<8; ++cch){
                // A: 4 k2-iters of the Wr stream
                #pragma unroll
                for (int u=0;u<4;++u){
                    const int i = cch*4+u;
                    const uint4 w = wp[(size_t)i*256];
                    const uint hv = hu[i];
                    za.x = dot2f(w.x,hv,za.x); za.y = dot2f(w.y,hv,za.y);
                    za.z = dot2f(w.z,hv,za.z); za.w = dot2f(w.w,hv,za.w);
                }
                // C: 8 tanh evals
                const uint4 pv = prow[cch*4 + sub];
                const int m = cch*32 + sub*8;
                const float4 qv0 = *(const float4*)(&s_q[m]);
                const float4 qv1 = *(const float4*)(&s_q[m+4]);
                const float4 wv0 = *(const float4*)(&s_Wv[m]);
                const float4 wv1 = *(const float4*)(&s_Wv[m+4]);
                const float2 p0 = __half22float2(__builtin_bit_cast(__half2, pv.x));
                const float2 p1 = __half22float2(__builtin_bit_cast(__half2, pv.y));
                const float2 p2 = __half22float2(__builtin_bit_cast(__half2, pv.z));
                const float2 p3 = __half22float2(__builtin_bit_cast(__half2, pv.w));
                sacc = fmaf(wv0.x, ftanh(p0.x+qv0.x), sacc);
                sacc = fmaf(wv0.y, ftanh(p0.y+qv0.y), sacc);
                sacc = fmaf(wv0.z, ftanh(p1.x+qv0.z), sacc);
                sacc = fmaf(wv0.w, ftanh(p1.y+qv0.w), sacc);
                sacc = fmaf(wv1.x, ftanh(p2.x+qv1.x), sacc);
                sacc = fmaf(wv1.y, ftanh(p2.y+qv1.y), sacc);
                sacc = fmaf(wv1.z, ftanh(p3.x+qv1.z), sacc);
                sacc = fmaf(wv1.w, ftanh(p3.y+qv1.w), sacc);
            }
            *(float4*)&s_red[kc*1024 + jq*4] = za;
            sacc += __shfl_xor(sacc,1);
            sacc += __shfl_xor(sacc,2);
            const float sc = sacc + s_sc2[1];
            if (sub==0) s_score[ttx] = sc;
            float mpart = (sub==0) ? sc : -1e30f;
            mpart = wmax(mpart);
            if (lane==0) s_r2[4+wid] = mpart;   // 16 wave maxima
        }
        __syncthreads();

        // ---- Phase 5: softmax numerator + xin partials (256 threads) ----
        if (tid < TT){
            float mx = s_r2[4];
            #pragma unroll
            for (int i=1;i<16;++i) mx = fmaxf(mx, s_r2[4+i]);
            const float e = __expf(s_score[tid]-mx);
            s_score[tid] = e;                      // kept for epilogue beta
            const float pe = e * s_edot[tid];
            const float se = wsum(e);
            const float sp = wsum(pe);
            if (lane==0){ s_r2[20+wid]=se; s_r2[24+wid]=sp; }
        }
        __syncthreads();
    }

    // ---- epilogue: ctx once from final beta ----
    {
        float4 ca = make_float4(0.f,0.f,0.f,0.f);
        const float* ep = erow_b + (size_t)(kc2*16)*MM + mq*4;
        #pragma unroll 4
        for (int k=0;k<16;++k){
            const float bt = s_score[kc2*16+k];
            const float4 e = *(const float4*)(ep);
            ca.x = fmaf(bt,e.x,ca.x); ca.y = fmaf(bt,e.y,ca.y);
            ca.z = fmaf(bt,e.z,ca.z); ca.w = fmaf(bt,e.w,ca.w);
            ep += MM;
        }
        *(float4*)&s_red[kc2*256 + mq*4] = ca;
    }
    __syncthreads();
    if (tid < MM){
        const float den = s_r2[20]+s_r2[21]+s_r2[22]+s_r2[23];
        const float rd = frcp(den);
        float s = 0.f;
        #pragma unroll
        for (int i=0;i<16;++i) s += s_red[i*256+tid];
        out[(size_t)b*512 + 256 + tid] = s*rd;
        out[(size_t)b*512 + tid]       = s_h[tid];
    }
}

extern "C" void kernel_launch(void* const* d_in, const int* in_sizes, int n_in,
                              void* d_out, int out_size, void* d_ws, size_t ws_size,
                              hipStream_t stream) {
    const float* data = (const float*)d_in[0];
    const float* enc  = (const float*)d_in[1];
    const float* h0   = (const float*)d_in[2];
    const float* c0   = (const float*)d_in[3];
    const float* Wd   = (const float*)d_in[4];
    const float* bd   = (const float*)d_in[5];
    const float* Wk   = (const float*)d_in[6];
    const float* Wr   = (const float*)d_in[7];
    const float* bl   = (const float*)d_in[8];
    const float* W1   = (const float*)d_in[9];
    const float* b1   = (const float*)d_in[10];
    const float* W2   = (const float*)d_in[11];
    const float* b2   = (const float*)d_in[12];
    const float* Wv   = (const float*)d_in[13];
    const float* bv   = (const float*)d_in[14];
    float* outp = (float*)d_out;

    char* ws = (char*)d_ws;
    __half*  pre  = (__half*)(ws);                            // 16,777,216 B
    __half2* Wr_p = (__half2*)(ws + 16777216);                //    524,288 B
    __half2* W2_p = (__half2*)(ws + 16777216 + 524288);       //    262,144 B
    float*   edot = (float*)(ws + 16777216 + 524288 + 262144);//    131,072 B

    prep_pre<<<dim3((NB*TT)/32), dim3(256), 0, stream>>>(enc, W1, b1, pre);
    pack_wr<<<dim3(512), dim3(256), 0, stream>>>(Wr, Wr_p);
    pack_w2<<<dim3(256), dim3(256), 0, stream>>>(W2, W2_p);
    prep_edot<<<dim3((NB*TT)/4), dim3(256), 0, stream>>>(enc, Wd, edot);
    decoder_kernel<<<dim3(NB), dim3(1024), 0, stream>>>(
        data, enc, h0, c0, Wd, bd, Wk, bl, b2, Wv, bv,
        (const uint4*)Wr_p, (const uint4*)W2_p, pre, edot, outp);
}

// Round 4
// 3921.849 us; speedup vs baseline: 1.4721x; 1.4721x over previous
//
#include <hip/hip_runtime.h>
#include <hip/hip_fp16.h>

#define NB 128
#define TT 256
#define MM 256
#define PP 256

typedef unsigned int uint;
typedef _Float16 hf2 __attribute__((ext_vector_type(2)));

__device__ __forceinline__ float dot2f(uint a, uint b, float c){
#if defined(__AMDGCN__) && __has_builtin(__builtin_amdgcn_fdot2)
    return __builtin_amdgcn_fdot2(__builtin_bit_cast(hf2, a), __builtin_bit_cast(hf2, b), c, false);
#else
    float2 fa = __half22float2(__builtin_bit_cast(__half2, a));
    float2 fb = __half22float2(__builtin_bit_cast(__half2, b));
    return fmaf(fa.x, fb.x, fmaf(fa.y, fb.y, c));
#endif
}

__device__ __forceinline__ float frcp(float x){ return __builtin_amdgcn_rcpf(x); }
__device__ __forceinline__ float fsig(float x){ return frcp(1.f + __expf(-x)); }
__device__ __forceinline__ float ftanh(float x){ return fmaf(-2.f, frcp(1.f + __expf(2.f*x)), 1.f); }

__device__ __forceinline__ float wsum(float v){
    #pragma unroll
    for(int o=32;o;o>>=1) v += __shfl_xor(v,o);
    return v;
}
__device__ __forceinline__ float wmax(float v){
    #pragma unroll
    for(int o=32;o;o>>=1) v = fmaxf(v,__shfl_xor(v,o));
    return v;
}

// pre[row, m] = sum_k enc[row, k] * W1[k, m] + b1[m] -> fp16
__global__ __launch_bounds__(256) void prep_pre(
    const float* __restrict__ enc, const float* __restrict__ W1,
    const float* __restrict__ b1, __half* __restrict__ pre)
{
    const int row0 = blockIdx.x * 32;
    const int col  = threadIdx.x;
    float acc[32];
    const float bias = b1[col];
    #pragma unroll
    for (int r=0;r<32;++r) acc[r]=bias;
    for (int k=0;k<256;k+=4){
        const float w0 = W1[(size_t)(k+0)*256+col];
        const float w1 = W1[(size_t)(k+1)*256+col];
        const float w2 = W1[(size_t)(k+2)*256+col];
        const float w3 = W1[(size_t)(k+3)*256+col];
        #pragma unroll
        for (int r=0;r<32;++r){
            const float4 e = *(const float4*)(enc + (size_t)(row0+r)*256 + k);
            acc[r] = fmaf(e.x,w0, fmaf(e.y,w1, fmaf(e.z,w2, fmaf(e.w,w3, acc[r]))));
        }
    }
    #pragma unroll
    for (int r=0;r<32;++r) pre[(size_t)(row0+r)*256+col] = __float2half(acc[r]);
}

// Wr (256,1024) f32 -> k-pair-interleaved half2: Wp[k2*1024 + j] = (Wr[2k2][j], Wr[2k2+1][j])
__global__ __launch_bounds__(256) void pack_wr(const float* __restrict__ Wr, __half2* __restrict__ Wp){
    const int idx = blockIdx.x*256 + threadIdx.x;   // 131072
    const int k2 = idx >> 10, j = idx & 1023;
    Wp[idx] = __floats2half2_rn(Wr[(size_t)(2*k2)*1024 + j], Wr[(size_t)(2*k2+1)*1024 + j]);
}
// W2 (512,256) f32 -> Wp[k2*256 + m]
__global__ __launch_bounds__(256) void pack_w2(const float* __restrict__ W2, __half2* __restrict__ Wp){
    const int idx = blockIdx.x*256 + threadIdx.x;   // 65536
    const int k2 = idx >> 8, m = idx & 255;
    Wp[idx] = __floats2half2_rn(W2[(size_t)(2*k2)*256 + m], W2[(size_t)(2*k2+1)*256 + m]);
}
// edot[row] = enc[row,:] . Wd[1:257]   (one 64-lane wave per row)
__global__ __launch_bounds__(256) void prep_edot(
    const float* __restrict__ enc, const float* __restrict__ Wd, float* __restrict__ edot)
{
    const int row  = blockIdx.x*4 + (threadIdx.x>>6);
    const int lane = threadIdx.x & 63;
    const float4 e = *(const float4*)(enc + (size_t)row*256 + lane*4);
    float s = e.x*Wd[1+lane*4] + e.y*Wd[2+lane*4] + e.z*Wd[3+lane*4] + e.w*Wd[4+lane*4];
    s = wsum(s);
    if (lane==0) edot[row] = s;
}

// One block per batch element; 1024 threads; full 255-step recurrence in-kernel.
// pre[b] (128KB fp16) lives in LDS, XOR-swizzled (16B chunk ^ (row&7)) for
// conflict-free ds_read_b128 in the score phase.
__global__ __launch_bounds__(1024) void decoder_kernel(
    const float* __restrict__ data, const float* __restrict__ enc,
    const float* __restrict__ h0, const float* __restrict__ c0,
    const float* __restrict__ Wd, const float* __restrict__ bd,
    const float* __restrict__ Wk, const float* __restrict__ bl,
    const float* __restrict__ b2, const float* __restrict__ Wv,
    const float* __restrict__ bv,
    const uint4* __restrict__ Wr_p,   // [128 k2][256 uint4]
    const uint4* __restrict__ W2_p,   // [256 k2][64 uint4]
    const __half* __restrict__ pre,   // [B*T][256]
    const float* __restrict__ edot,   // [B*T]
    float* __restrict__ out)
{
    __shared__ __half s_pre[TT*MM];      // 131072 B, swizzled
    __shared__ float s_red[4096];        // 16384 B
    __shared__ float s_h[PP], s_c[PP], s_q[MM], s_score[TT];
    __shared__ float s_r2[32];
    __shared__ __half s_Wk[1024];
    __shared__ float s_bl[1024], s_b2[MM], s_Wv[MM];
    __shared__ float s_edot[TT], s_data[TT];
    __shared__ float s_sc2[4];
    __shared__ __half s_hh[PP], s_ch[PP];

    const int b    = blockIdx.x;
    const int tid  = threadIdx.x;
    const int lane = tid & 63;
    const int wid  = tid >> 6;

    s_Wk[tid] = __float2half(Wk[tid]);
    s_bl[tid] = bl[tid];
    if (tid < MM){
        s_b2[tid] = b2[tid];
        s_Wv[tid] = Wv[tid];
        const float h0v = h0[(size_t)b*PP+tid];
        const float c0v = c0[(size_t)b*PP+tid];
        s_h[tid]  = h0v;  s_hh[tid] = __float2half(h0v);
        s_c[tid]  = c0v;  s_ch[tid] = __float2half(c0v);
        s_edot[tid] = edot[(size_t)b*TT + tid];
    }
    if (tid < TT-1) s_data[tid] = data[(size_t)b*(TT-1)+tid];
    if (tid < 8)  s_r2[20+tid] = (tid==0) ? 1.f : 0.f;   // den=1, num=0 -> ctx term 0
    if (tid == 0){ s_sc2[0] = bd[0]; s_sc2[1] = bv[0]; s_sc2[2] = Wd[0]; }
    __syncthreads();

    const float* erow_b = enc + (size_t)b*TT*MM;

    const int jq  = tid & 255;   // A: j-quad
    const int kc  = tid >> 8;    // A: k2-chunk 0..3 (32 k2 each)
    const int mq  = tid & 63;    // B/epilogue: m-quad
    const int kc2 = tid >> 6;    // B: k2-chunk 0..15; epilogue: t-chunk
    const int ttx = tid >> 2;    // C: t index
    const int sub = tid & 3;     // C: m sub-chunk

    // ---- prologue: stage pre[b] into LDS (swizzled) + z-partials for h0 ----
    {
        // pre copy: thread -> row t0 = tid>>2, chunks c0..c0+7 (16B each)
        const uint4* g = (const uint4*)(pre + (size_t)b*TT*MM);
        const int t0 = tid >> 2, c0 = (tid & 3) * 8;
        #pragma unroll
        for (int i=0;i<8;++i){
            const int c = c0 + i;
            const uint4 v = g[t0*32 + c];
            *(uint4*)((char*)s_pre + t0*512 + ((c*16) ^ ((t0&7)<<4))) = v;
        }
        // z-partials for h0
        float4 za = make_float4(0.f,0.f,0.f,0.f);
        const uint4* wp = Wr_p + (size_t)(kc*32)*256 + jq;
        const uint*  hu = ((const uint*)s_hh) + kc*32;
        #pragma unroll 8
        for (int i=0;i<32;++i){
            const uint4 w = wp[(size_t)i*256];
            const uint hv = hu[i];
            za.x = dot2f(w.x,hv,za.x); za.y = dot2f(w.y,hv,za.y);
            za.z = dot2f(w.z,hv,za.z); za.w = dot2f(w.w,hv,za.w);
        }
        *(float4*)&s_red[kc*1024 + jq*4] = za;
    }
    __syncthreads();

    for (int t=0; t<TT-1; ++t){
        // ---- Phase 1: gates (256 threads) ----
        if (tid < PP){
            const float den = s_r2[20]+s_r2[21]+s_r2[22]+s_r2[23];
            const float num = s_r2[24]+s_r2[25]+s_r2[26]+s_r2[27];
            const float xin = num*frcp(den) + s_data[t]*s_sc2[2] + s_sc2[0];
            float z[4];
            #pragma unroll
            for (int g=0; g<4; ++g){
                const int j = tid + 256*g;
                float zz = s_red[j] + s_red[1024+j] + s_red[2048+j] + s_red[3072+j];
                z[g] = zz + xin*__half2float(s_Wk[j]) + s_bl[j];
            }
            const float gi = fsig(z[0]);
            const float gf = fsig(z[1]);
            const float gg = ftanh(z[2]);
            const float go = fsig(z[3]);
            const float c_new = gf*s_c[tid] + gi*gg;
            const float h_new = go*ftanh(c_new);
            s_c[tid] = c_new;
            s_h[tid] = h_new;
            s_hh[tid] = __float2half(h_new);
            s_ch[tid] = __float2half(c_new);
        }
        __syncthreads();

        // ---- Phase 2: q partials, [h;c] @ W2 via dot2 ----
        {
            float4 qa = make_float4(0.f,0.f,0.f,0.f);
            const uint4* wp = W2_p + (size_t)(kc2*16)*64 + mq;
            const uint*  hb = (kc2 < 8) ? (const uint*)s_hh : (((const uint*)s_ch) - 128);
            #pragma unroll 8
            for (int i=0;i<16;++i){
                const uint4 w = wp[(size_t)i*64];
                const uint hv = hb[kc2*16 + i];
                qa.x = dot2f(w.x,hv,qa.x); qa.y = dot2f(w.y,hv,qa.y);
                qa.z = dot2f(w.z,hv,qa.z); qa.w = dot2f(w.w,hv,qa.w);
            }
            *(float4*)&s_red[kc2*256 + mq*4] = qa;
        }
        __syncthreads();

        // ---- Phase 3: q reduce (256 threads) ----
        if (tid < MM){
            float q = s_b2[tid];
            #pragma unroll
            for (int i=0;i<16;++i) q += s_red[i*256+tid];
            s_q[tid] = q;
        }
        __syncthreads();

        // ---- Phase 4 (fused): scores (tanh, pre from LDS) + next-step z-partials (Wr L2 stream) ----
        {
            float4 za = make_float4(0.f,0.f,0.f,0.f);
            float sacc = 0.f;
            const uint4* wp = Wr_p + (size_t)(kc*32)*256 + jq;
            const uint*  hu = ((const uint*)s_hh) + kc*32;
            const char* prow = (const char*)s_pre + ttx*512;
            const int rsw = (ttx&7)<<4;
            #pragma unroll
            for (int cch=0; cch<8; ++cch){
                // A: 4 k2-iters of the Wr stream
                #pragma unroll
                for (int u=0;u<4;++u){
                    const int i = cch*4+u;
                    const uint4 w = wp[(size_t)i*256];
                    const uint hv = hu[i];
                    za.x = dot2f(w.x,hv,za.x); za.y = dot2f(w.y,hv,za.y);
                    za.z = dot2f(w.z,hv,za.z); za.w = dot2f(w.w,hv,za.w);
                }
                // C: 8 tanh evals (pre from swizzled LDS)
                const uint4 pv = *(const uint4*)(prow + (((cch*4+sub)*16) ^ rsw));
                const int m = cch*32 + sub*8;
                const float4 qv0 = *(const float4*)(&s_q[m]);
                const float4 qv1 = *(const float4*)(&s_q[m+4]);
                const float4 wv0 = *(const float4*)(&s_Wv[m]);
                const float4 wv1 = *(const float4*)(&s_Wv[m+4]);
                const float2 p0 = __half22float2(__builtin_bit_cast(__half2, pv.x));
                const float2 p1 = __half22float2(__builtin_bit_cast(__half2, pv.y));
                const float2 p2 = __half22float2(__builtin_bit_cast(__half2, pv.z));
                const float2 p3 = __half22float2(__builtin_bit_cast(__half2, pv.w));
                sacc = fmaf(wv0.x, ftanh(p0.x+qv0.x), sacc);
                sacc = fmaf(wv0.y, ftanh(p0.y+qv0.y), sacc);
                sacc = fmaf(wv0.z, ftanh(p1.x+qv0.z), sacc);
                sacc = fmaf(wv0.w, ftanh(p1.y+qv0.w), sacc);
                sacc = fmaf(wv1.x, ftanh(p2.x+qv1.x), sacc);
                sacc = fmaf(wv1.y, ftanh(p2.y+qv1.y), sacc);
                sacc = fmaf(wv1.z, ftanh(p3.x+qv1.z), sacc);
                sacc = fmaf(wv1.w, ftanh(p3.y+qv1.w), sacc);
            }
            *(float4*)&s_red[kc*1024 + jq*4] = za;
            sacc += __shfl_xor(sacc,1);
            sacc += __shfl_xor(sacc,2);
            const float sc = sacc + s_sc2[1];
            if (sub==0) s_score[ttx] = sc;
            float mpart = (sub==0) ? sc : -1e30f;
            mpart = wmax(mpart);
            if (lane==0) s_r2[4+wid] = mpart;   // 16 wave maxima
        }
        __syncthreads();

        // ---- Phase 5: softmax numerator + xin partials (256 threads) ----
        if (tid < TT){
            float mx = s_r2[4];
            #pragma unroll
            for (int i=1;i<16;++i) mx = fmaxf(mx, s_r2[4+i]);
            const float e = __expf(s_score[tid]-mx);
            s_score[tid] = e;                      // kept for epilogue beta
            const float pe = e * s_edot[tid];
            const float se = wsum(e);
            const float sp = wsum(pe);
            if (lane==0){ s_r2[20+wid]=se; s_r2[24+wid]=sp; }
        }
        __syncthreads();
    }

    // ---- epilogue: ctx once from final beta ----
    {
        float4 ca = make_float4(0.f,0.f,0.f,0.f);
        const float* ep = erow_b + (size_t)(kc2*16)*MM + mq*4;
        #pragma unroll 4
        for (int k=0;k<16;++k){
            const float bt = s_score[kc2*16+k];
            const float4 e = *(const float4*)(ep);
            ca.x = fmaf(bt,e.x,ca.x); ca.y = fmaf(bt,e.y,ca.y);
            ca.z = fmaf(bt,e.z,ca.z); ca.w = fmaf(bt,e.w,ca.w);
            ep += MM;
        }
        *(float4*)&s_red[kc2*256 + mq*4] = ca;
    }
    __syncthreads();
    if (tid < MM){
        const float den = s_r2[20]+s_r2[21]+s_r2[22]+s_r2[23];
        const float rd = frcp(den);
        float s = 0.f;
        #pragma unroll
        for (int i=0;i<16;++i) s += s_red[i*256+tid];
        out[(size_t)b*512 + 256 + tid] = s*rd;
        out[(size_t)b*512 + tid]       = s_h[tid];
    }
}

extern "C" void kernel_launch(void* const* d_in, const int* in_sizes, int n_in,
                              void* d_out, int out_size, void* d_ws, size_t ws_size,
                              hipStream_t stream) {
    const float* data = (const float*)d_in[0];
    const float* enc  = (const float*)d_in[1];
    const float* h0   = (const float*)d_in[2];
    const float* c0   = (const float*)d_in[3];
    const float* Wd   = (const float*)d_in[4];
    const float* bd   = (const float*)d_in[5];
    const float* Wk   = (const float*)d_in[6];
    const float* Wr   = (const float*)d_in[7];
    const float* bl   = (const float*)d_in[8];
    const float* W1   = (const float*)d_in[9];
    const float* b1   = (const float*)d_in[10];
    const float* W2   = (const float*)d_in[11];
    const float* b2   = (const float*)d_in[12];
    const float* Wv   = (const float*)d_in[13];
    const float* bv   = (const float*)d_in[14];
    float* outp = (float*)d_out;

    char* ws = (char*)d_ws;
    __half*  pre  = (__half*)(ws);                            // 16,777,216 B
    __half2* Wr_p = (__half2*)(ws + 16777216);                //    524,288 B
    __half2* W2_p = (__half2*)(ws + 16777216 + 524288);       //    262,144 B
    float*   edot = (float*)(ws + 16777216 + 524288 + 262144);//    131,072 B

    prep_pre<<<dim3((NB*TT)/32), dim3(256), 0, stream>>>(enc, W1, b1, pre);
    pack_wr<<<dim3(512), dim3(256), 0, stream>>>(Wr, Wr_p);
    pack_w2<<<dim3(256), dim3(256), 0, stream>>>(W2, W2_p);
    prep_edot<<<dim3((NB*TT)/4), dim3(256), 0, stream>>>(enc, Wd, edot);
    decoder_kernel<<<dim3(NB), dim3(1024), 0, stream>>>(
        data, enc, h0, c0, Wd, bd, Wk, bl, b2, Wv, bv,
        (const uint4*)Wr_p, (const uint4*)W2_p, pre, edot, outp);
}